// Round 5
// baseline (196.786 us; speedup 1.0000x reference)
//
#include <hip/hip_runtime.h>
#include <stdint.h>
#include <math.h>

typedef __attribute__((ext_vector_type(8))) __bf16 bf16x8;
typedef __attribute__((ext_vector_type(4))) __bf16 bf16x4;
typedef __attribute__((ext_vector_type(4))) float f32x4;

// ---------------- gates: softmax(x @ W_aux^T + b_aux) ----------------
// block 0 also zeroes the atomic accumulators (replaces the memset node).
__global__ __launch_bounds__(256) void k_gates(const float* __restrict__ x,
                                               const float* __restrict__ Waux,
                                               const float* __restrict__ baux,
                                               float* __restrict__ gates,
                                               float* __restrict__ colsum,
                                               float* __restrict__ scal) {
  if (blockIdx.x == 0) {
    colsum[threadIdx.x] = 0.f;
    if (threadIdx.x < 8) scal[threadIdx.x] = 0.f;
  }
  const int wave = threadIdx.x >> 6;
  const int lane = threadIdx.x & 63;
  const int row = blockIdx.x * 4 + wave;
  const float4* xr = (const float4*)(x + (size_t)row * 512);
  const float4* w0 = (const float4*)(Waux);
  const float4* w1 = (const float4*)(Waux + 512);
  float p0 = 0.f, p1 = 0.f;
  for (int c = lane; c < 128; c += 64) {
    float4 xv = xr[c];
    float4 a = w0[c], b = w1[c];
    p0 += xv.x * a.x + xv.y * a.y + xv.z * a.z + xv.w * a.w;
    p1 += xv.x * b.x + xv.y * b.y + xv.z * b.z + xv.w * b.w;
  }
  for (int off = 32; off; off >>= 1) {
    p0 += __shfl_down(p0, off, 64);
    p1 += __shfl_down(p1, off, 64);
  }
  if (lane == 0) {
    p0 += baux[0]; p1 += baux[1];
    float m = fmaxf(p0, p1);
    float e0 = __expf(p0 - m), e1 = __expf(p1 - m);
    float inv = 1.f / (e0 + e1);
    gates[row * 2 + 0] = e0 * inv;
    gates[row * 2 + 1] = e1 * inv;
  }
}

// ---------------- outs GEMM: C[m][n] = sum_k x[m][k] * Wflat[n][k] + bias[n] ----
// M=4096, N=512, K=512. 64x64 tiles -> grid (8,64)=512 blocks.
__global__ __launch_bounds__(256) void k_outs(const float* __restrict__ x,
                                              const float* __restrict__ W,
                                              const float* __restrict__ bias,
                                              __bf16* __restrict__ totalbf) {
  __shared__ __bf16 As[64][64];
  __shared__ __bf16 Bs[64][64];
  const int bj = blockIdx.x;   // 0..7  (N tiles of 64)
  const int bi = blockIdx.y;   // 0..63 (M tiles of 64)
  const int t = threadIdx.x;
  const int wid = t >> 6, lane = t & 63;
  const int wr = wid >> 1, wc = wid & 1;
  const int n16 = lane & 15, q = lane >> 4;
  const int sx = (n16 & 7) << 3;        // read-side swizzle (element units)
  const int erow = t >> 4;              // 0..15 (+p*16)
  const int c4 = (t & 15) << 2;         // 0..60

  f32x4 acc[2][2];
  f32x4 zero = {0.f, 0.f, 0.f, 0.f};
  for (int i = 0; i < 2; ++i)
    for (int j = 0; j < 2; ++j) acc[i][j] = zero;

  const int arow0 = bi * 64, brow0 = bj * 64;

  float4 ra[4], rb[4];
#pragma unroll
  for (int p = 0; p < 4; ++p) {
    int row = p * 16 + erow;
    ra[p] = *(const float4*)(x + (size_t)(arow0 + row) * 512 + c4);
    rb[p] = *(const float4*)(W + (size_t)(brow0 + row) * 512 + c4);
  }

  for (int kc = 0; kc < 512; kc += 64) {
#pragma unroll
    for (int p = 0; p < 4; ++p) {
      int row = p * 16 + erow;
      int col = c4 ^ ((row & 7) << 3);
      float4 va = ra[p];
      bf16x4 ba = {(__bf16)va.x, (__bf16)va.y, (__bf16)va.z, (__bf16)va.w};
      *(bf16x4*)&As[row][col] = ba;
      float4 vb = rb[p];
      bf16x4 bb = {(__bf16)vb.x, (__bf16)vb.y, (__bf16)vb.z, (__bf16)vb.w};
      *(bf16x4*)&Bs[row][col] = bb;
    }
    __syncthreads();
    // issue next-tile global loads AFTER the barrier: they fly under the MFMAs
    if (kc < 448) {
#pragma unroll
      for (int p = 0; p < 4; ++p) {
        int row = p * 16 + erow;
        ra[p] = *(const float4*)(x + (size_t)(arow0 + row) * 512 + kc + 64 + c4);
        rb[p] = *(const float4*)(W + (size_t)(brow0 + row) * 512 + kc + 64 + c4);
      }
    }
#pragma unroll
    for (int ks = 0; ks < 2; ++ks) {
      bf16x8 af[2], bfr[2];
#pragma unroll
      for (int f = 0; f < 2; ++f) {
        af[f]  = *(const bf16x8*)&As[wr * 32 + f * 16 + n16][(ks * 32 + q * 8) ^ sx];
        bfr[f] = *(const bf16x8*)&Bs[wc * 32 + f * 16 + n16][(ks * 32 + q * 8) ^ sx];
      }
      for (int fr = 0; fr < 2; ++fr)
        for (int fc = 0; fc < 2; ++fc)
          acc[fr][fc] = __builtin_amdgcn_mfma_f32_16x16x32_bf16(af[fr], bfr[fc], acc[fr][fc], 0, 0, 0);
    }
    __syncthreads();
  }

  for (int fc = 0; fc < 2; ++fc) {
    int n_g = bj * 64 + wc * 32 + fc * 16 + n16;   // 0..511
    float bv = bias[n_g];
    int l = n_g >> 8, o = n_g & 255;
    for (int fr = 0; fr < 2; ++fr) {
      for (int r = 0; r < 4; ++r) {
        int m_g = bi * 64 + wr * 32 + fr * 16 + q * 4 + r;
        float v = acc[fr][fc][r] + bv;
        totalbf[(size_t)(l * 4096 + m_g) * 256 + o] = (__bf16)v;
      }
    }
  }
}

// ------- fused: sq + colsum + combine + bandwidth finalize (last block) -------
__global__ __launch_bounds__(256) void k_sqc(const __bf16* __restrict__ tot,
                                             const float* __restrict__ gates,
                                             float* __restrict__ sq,
                                             float* __restrict__ colsum,
                                             float* __restrict__ scal,
                                             float* __restrict__ out) {
  __shared__ float lcol[4][256];
  __shared__ float wsq[4];
  __shared__ unsigned int isLast;
  const int t = threadIdx.x;
  const int wave = t >> 6, lane = t & 63;
  float c0 = 0.f, c1 = 0.f, c2 = 0.f, c3 = 0.f;
  float bsq = 0.f;
  for (int it = 0; it < 8; ++it) {
    int m = blockIdx.x * 32 + wave * 8 + it;      // 0..4095
    bf16x4 v0 = *(const bf16x4*)(tot + (size_t)m * 256 + lane * 4);
    bf16x4 v1 = *(const bf16x4*)(tot + (size_t)(4096 + m) * 256 + lane * 4);
    float f00 = v0[0], f01 = v0[1], f02 = v0[2], f03 = v0[3];
    float f10 = v1[0], f11 = v1[1], f12 = v1[2], f13 = v1[3];
    float s0 = f00 * f00 + f01 * f01 + f02 * f02 + f03 * f03;
    float s1 = f10 * f10 + f11 * f11 + f12 * f12 + f13 * f13;
    for (int off = 32; off; off >>= 1) {
      s0 += __shfl_down(s0, off, 64);
      s1 += __shfl_down(s1, off, 64);
    }
    if (lane == 0) { sq[m] = s0; sq[4096 + m] = s1; bsq += s0 + s1; }
    c0 += f00 + f10; c1 += f01 + f11; c2 += f02 + f12; c3 += f03 + f13;
    float2 gv = *(const float2*)(gates + m * 2);
    float4 r;
    r.x = gv.x * f00 + gv.y * f10;
    r.y = gv.x * f01 + gv.y * f11;
    r.z = gv.x * f02 + gv.y * f12;
    r.w = gv.x * f03 + gv.y * f13;
    *(float4*)(out + (size_t)m * 256 + lane * 4) = r;
  }
  lcol[wave][lane * 4 + 0] = c0;
  lcol[wave][lane * 4 + 1] = c1;
  lcol[wave][lane * 4 + 2] = c2;
  lcol[wave][lane * 4 + 3] = c3;
  if (lane == 0) wsq[wave] = bsq;
  __syncthreads();
  float s2 = lcol[0][t] + lcol[1][t] + lcol[2][t] + lcol[3][t];
  atomicAdd(&colsum[t], s2);
  if (t == 0) atomicAdd(&scal[4], wsq[0] + wsq[1] + wsq[2] + wsq[3]);
  __threadfence();
  if (t == 0) {
    unsigned int c = atomicAdd((unsigned int*)(scal + 5), 1u);
    isLast = (c == 127u) ? 1u : 0u;
  }
  __syncthreads();
  if (isLast) {
    __threadfence();
    float cv = atomicAdd(&colsum[t], 0.0f);      // coherent read
    lcol[0][t] = cv * cv;
    __syncthreads();
    for (int off = 128; off; off >>= 1) {
      if (t < off) lcol[0][t] += lcol[0][t + off];
      __syncthreads();
    }
    if (t == 0) {
      float sumsq = atomicAdd(&scal[4], 0.0f);
      double sumdist = 2.0 * 8192.0 * (double)sumsq - 2.0 * (double)lcol[0][0];
      double bw = sumdist / (8192.0 * 8192.0 - 8192.0) / 4.0;  // / KERNEL_MUL^(5//2)
      scal[1] = (float)(1.4426950408889634 / (bw * 16.0));     // g4 * log2(e)
      scal[2] = (float)bw;
    }
  }
}

// ---------------- Gram tiles + fused multi-bandwidth kernel sum ---------------
// Compact upper-triangle launch (2080 = 8 XCDs x 260, balanced, bijective).
// DIRECT-FRAGMENT version: totalbf (4 MB) is fully L2/L3-resident, and the
// 16x16x32 A/B fragment is a contiguous 16B row-slice -> load fragments
// straight from global (one dwordx4 each). No LDS tiles, no barriers, no
// staging pipeline: each wave is pure dataflow (64 loads || 128 MFMAs), the
// compiler pipelines freely, occupancy cap rises from 8 to 20+ waves/CU.
// (R2-R4 showed every LDS-staging schedule is latency-serialized here;
// MFMA work is only ~2.2 us — staging cache-fit data was pure overhead.)
__global__ __launch_bounds__(256) void k_gram(const __bf16* __restrict__ tot,
                                              const float* __restrict__ sq,
                                              const float* __restrict__ scal,
                                              float* __restrict__ Ssum,
                                              float* __restrict__ out) {
  const int b = blockIdx.x;                    // 0..2079
  const int nid = (b & 7) * 260 + (b >> 3);    // XCD-chunked, bijective
  int ti = (int)((129.0 - sqrt(129.0 * 129.0 - 8.0 * (double)nid)) * 0.5);
  while (64 * ti - ti * (ti - 1) / 2 > nid) --ti;
  while (64 * (ti + 1) - (ti + 1) * ti / 2 <= nid) ++ti;
  const int tj = ti + (nid - (64 * ti - ti * (ti - 1) / 2));

  __shared__ float sqi[128], sqj[128];
  __shared__ float wred[4];
  const int t = threadIdx.x;
  const int wid = t >> 6, lane = t & 63;
  const int wr = wid >> 1, wc = wid & 1;
  const int n16 = lane & 15, q = lane >> 4;

  const float g = scal[1];           // log2e / (bw*16)
  if (t < 128) sqi[t] = sq[ti * 128 + t] * g;
  else         sqj[t - 128] = sq[tj * 128 + (t - 128)] * g;

  f32x4 acc[4][4];
  f32x4 zero = {0.f, 0.f, 0.f, 0.f};
  for (int i = 0; i < 4; ++i)
    for (int j = 0; j < 4; ++j) acc[i][j] = zero;

  // per-lane fragment bases: A-frag f = 16B at row (ti*128+wr*64+f*16+n16),
  // cols ks*32+q*8 — contiguous, one global_load_dwordx4 each.
  const __bf16* pA = tot + (size_t)(ti * 128 + wr * 64 + n16) * 256 + q * 8;
  const __bf16* pB = tot + (size_t)(tj * 128 + wc * 64 + n16) * 256 + q * 8;

#pragma unroll
  for (int ks = 0; ks < 8; ++ks) {
    bf16x8 af[4], bfr[4];
#pragma unroll
    for (int f = 0; f < 4; ++f) {
      af[f]  = *(const bf16x8*)(pA + (size_t)f * 16 * 256 + ks * 32);
      bfr[f] = *(const bf16x8*)(pB + (size_t)f * 16 * 256 + ks * 32);
    }
    for (int fr = 0; fr < 4; ++fr)
      for (int fc = 0; fc < 4; ++fc)
        acc[fr][fc] = __builtin_amdgcn_mfma_f32_16x16x32_bf16(af[fr], bfr[fc], acc[fr][fc], 0, 0, 0);
  }

  __syncthreads();   // publish sqi/sqj (written at kernel start)

  // epilogue: arg = 2g*acc - (g*si + g*sj); ksum = u+u2+u4+u8+u16, u=exp2(arg)
  const float twog = 2.f * g;
  float lsum = 0.f;
  for (int fr = 0; fr < 4; ++fr) {
    for (int r = 0; r < 4; ++r) {
      float gsi = sqi[wr * 64 + fr * 16 + q * 4 + r];
      for (int fc = 0; fc < 4; ++fc) {
        float gsj = sqj[wc * 64 + fc * 16 + n16];
        float u = exp2f(fmaf(twog, acc[fr][fc][r], -(gsi + gsj)));
        float u2 = u * u, u4 = u2 * u2, u8 = u4 * u4;
        float s1 = fmaf(u8, u8, u8);           // u16 + u8
        lsum += (u + u2) + (u4 + s1);
      }
    }
  }
  for (int off = 32; off; off >>= 1) lsum += __shfl_down(lsum, off, 64);
  if (lane == 0) wred[wid] = lsum;
  __syncthreads();
  if (t == 0) {
    float blocksum = wred[0] + wred[1] + wred[2] + wred[3];
    float sgn = ((ti < 32) == (tj < 32)) ? 1.f : -1.f;
    float wgt = (ti == tj) ? sgn : 2.f * sgn;
    atomicAdd(Ssum, wgt * blocksum);
    __threadfence();
    unsigned int* cnt = (unsigned int*)(Ssum + 3);   // scal[3], zeroed by k_gates
    unsigned int c = atomicAdd(cnt, 1u);
    if (c == 2079u) {
      float totS = atomicAdd(Ssum, 0.0f);            // coherent read of full sum
      out[1048576] = -(totS / 16777216.0f);
    }
  }
}

extern "C" void kernel_launch(void* const* d_in, const int* in_sizes, int n_in,
                              void* d_out, int out_size, void* d_ws, size_t ws_size,
                              hipStream_t stream) {
  const float* x    = (const float*)d_in[0];
  const float* Waux = (const float*)d_in[1];
  const float* baux = (const float*)d_in[2];
  const float* W    = (const float*)d_in[3];
  const float* bias = (const float*)d_in[4];
  float* out = (float*)d_out;

  char* ws = (char*)d_ws;
  __bf16* totalbf = (__bf16*)ws;                    // 8192*256*2 = 4,194,304 B
  float* sq      = (float*)(ws + 4194304);          // 8192 f32
  float* colsum  = (float*)(ws + 4227072);          // 256 f32
  float* scal    = (float*)(ws + 4228096);          // [0]=Ssum [1]=g4l2 [2]=bw [3]=gram-cnt [4]=sumsq [5]=sqc-cnt
  float* gates   = (float*)(ws + 4228160);          // 4096*2 f32

  k_gates<<<1024, 256, 0, stream>>>(x, Waux, baux, gates, colsum, scal);
  k_outs<<<dim3(8, 64), 256, 0, stream>>>(x, W, bias, totalbf);
  k_sqc<<<128, 256, 0, stream>>>(totalbf, gates, sq, colsum, scal, out);
  k_gram<<<2080, 256, 0, stream>>>(totalbf, sq, scal, scal, out);
}

// Round 6
// 173.686 us; speedup vs baseline: 1.1330x; 1.1330x over previous
//
#include <hip/hip_runtime.h>
#include <stdint.h>
#include <math.h>

typedef __attribute__((ext_vector_type(8))) __bf16 bf16x8;
typedef __attribute__((ext_vector_type(4))) __bf16 bf16x4;
typedef __attribute__((ext_vector_type(4))) float f32x4;

// async global->LDS 16B DMA (no VGPR round-trip). LDS dest must be
// wave-uniform base; HW writes lane i at base + i*16.
__device__ __forceinline__ void gload_lds16(const __bf16* g, __bf16* l) {
  __builtin_amdgcn_global_load_lds(
      (const __attribute__((address_space(1))) unsigned int*)g,
      (__attribute__((address_space(3))) unsigned int*)l,
      16, 0, 0);
}

// ---------------- gates: softmax(x @ W_aux^T + b_aux) ----------------
// block 0 also zeroes the atomic accumulators (replaces the memset node).
__global__ __launch_bounds__(256) void k_gates(const float* __restrict__ x,
                                               const float* __restrict__ Waux,
                                               const float* __restrict__ baux,
                                               float* __restrict__ gates,
                                               float* __restrict__ colsum,
                                               float* __restrict__ scal) {
  if (blockIdx.x == 0) {
    colsum[threadIdx.x] = 0.f;
    if (threadIdx.x < 8) scal[threadIdx.x] = 0.f;
  }
  const int wave = threadIdx.x >> 6;
  const int lane = threadIdx.x & 63;
  const int row = blockIdx.x * 4 + wave;
  const float4* xr = (const float4*)(x + (size_t)row * 512);
  const float4* w0 = (const float4*)(Waux);
  const float4* w1 = (const float4*)(Waux + 512);
  float p0 = 0.f, p1 = 0.f;
  for (int c = lane; c < 128; c += 64) {
    float4 xv = xr[c];
    float4 a = w0[c], b = w1[c];
    p0 += xv.x * a.x + xv.y * a.y + xv.z * a.z + xv.w * a.w;
    p1 += xv.x * b.x + xv.y * b.y + xv.z * b.z + xv.w * b.w;
  }
  for (int off = 32; off; off >>= 1) {
    p0 += __shfl_down(p0, off, 64);
    p1 += __shfl_down(p1, off, 64);
  }
  if (lane == 0) {
    p0 += baux[0]; p1 += baux[1];
    float m = fmaxf(p0, p1);
    float e0 = __expf(p0 - m), e1 = __expf(p1 - m);
    float inv = 1.f / (e0 + e1);
    gates[row * 2 + 0] = e0 * inv;
    gates[row * 2 + 1] = e1 * inv;
  }
}

// ---------------- outs GEMM: C[m][n] = sum_k x[m][k] * Wflat[n][k] + bias[n] ----
// M=4096, N=512, K=512. 64x64 tiles -> grid (8,64)=512 blocks.
__global__ __launch_bounds__(256) void k_outs(const float* __restrict__ x,
                                              const float* __restrict__ W,
                                              const float* __restrict__ bias,
                                              __bf16* __restrict__ totalbf) {
  __shared__ __bf16 As[64][64];
  __shared__ __bf16 Bs[64][64];
  const int bj = blockIdx.x;   // 0..7  (N tiles of 64)
  const int bi = blockIdx.y;   // 0..63 (M tiles of 64)
  const int t = threadIdx.x;
  const int wid = t >> 6, lane = t & 63;
  const int wr = wid >> 1, wc = wid & 1;
  const int n16 = lane & 15, q = lane >> 4;
  const int sx = (n16 & 7) << 3;        // read-side swizzle (element units)
  const int erow = t >> 4;              // 0..15 (+p*16)
  const int c4 = (t & 15) << 2;         // 0..60

  f32x4 acc[2][2];
  f32x4 zero = {0.f, 0.f, 0.f, 0.f};
  for (int i = 0; i < 2; ++i)
    for (int j = 0; j < 2; ++j) acc[i][j] = zero;

  const int arow0 = bi * 64, brow0 = bj * 64;

  float4 ra[4], rb[4];
#pragma unroll
  for (int p = 0; p < 4; ++p) {
    int row = p * 16 + erow;
    ra[p] = *(const float4*)(x + (size_t)(arow0 + row) * 512 + c4);
    rb[p] = *(const float4*)(W + (size_t)(brow0 + row) * 512 + c4);
  }

  for (int kc = 0; kc < 512; kc += 64) {
#pragma unroll
    for (int p = 0; p < 4; ++p) {
      int row = p * 16 + erow;
      int col = c4 ^ ((row & 7) << 3);
      float4 va = ra[p];
      bf16x4 ba = {(__bf16)va.x, (__bf16)va.y, (__bf16)va.z, (__bf16)va.w};
      *(bf16x4*)&As[row][col] = ba;
      float4 vb = rb[p];
      bf16x4 bb = {(__bf16)vb.x, (__bf16)vb.y, (__bf16)vb.z, (__bf16)vb.w};
      *(bf16x4*)&Bs[row][col] = bb;
    }
    __syncthreads();
    // issue next-tile global loads AFTER the barrier: they fly under the MFMAs
    if (kc < 448) {
#pragma unroll
      for (int p = 0; p < 4; ++p) {
        int row = p * 16 + erow;
        ra[p] = *(const float4*)(x + (size_t)(arow0 + row) * 512 + kc + 64 + c4);
        rb[p] = *(const float4*)(W + (size_t)(brow0 + row) * 512 + kc + 64 + c4);
      }
    }
#pragma unroll
    for (int ks = 0; ks < 2; ++ks) {
      bf16x8 af[2], bfr[2];
#pragma unroll
      for (int f = 0; f < 2; ++f) {
        af[f]  = *(const bf16x8*)&As[wr * 32 + f * 16 + n16][(ks * 32 + q * 8) ^ sx];
        bfr[f] = *(const bf16x8*)&Bs[wc * 32 + f * 16 + n16][(ks * 32 + q * 8) ^ sx];
      }
      for (int fr = 0; fr < 2; ++fr)
        for (int fc = 0; fc < 2; ++fc)
          acc[fr][fc] = __builtin_amdgcn_mfma_f32_16x16x32_bf16(af[fr], bfr[fc], acc[fr][fc], 0, 0, 0);
    }
    __syncthreads();
  }

  for (int fc = 0; fc < 2; ++fc) {
    int n_g = bj * 64 + wc * 32 + fc * 16 + n16;   // 0..511
    float bv = bias[n_g];
    int l = n_g >> 8, o = n_g & 255;
    for (int fr = 0; fr < 2; ++fr) {
      for (int r = 0; r < 4; ++r) {
        int m_g = bi * 64 + wr * 32 + fr * 16 + q * 4 + r;
        float v = acc[fr][fc][r] + bv;
        totalbf[(size_t)(l * 4096 + m_g) * 256 + o] = (__bf16)v;
      }
    }
  }
}

// ------- fused: sq + colsum + combine + bandwidth finalize (last block) -------
__global__ __launch_bounds__(256) void k_sqc(const __bf16* __restrict__ tot,
                                             const float* __restrict__ gates,
                                             float* __restrict__ sq,
                                             float* __restrict__ colsum,
                                             float* __restrict__ scal,
                                             float* __restrict__ out) {
  __shared__ float lcol[4][256];
  __shared__ float wsq[4];
  __shared__ unsigned int isLast;
  const int t = threadIdx.x;
  const int wave = t >> 6, lane = t & 63;
  float c0 = 0.f, c1 = 0.f, c2 = 0.f, c3 = 0.f;
  float bsq = 0.f;
  for (int it = 0; it < 8; ++it) {
    int m = blockIdx.x * 32 + wave * 8 + it;      // 0..4095
    bf16x4 v0 = *(const bf16x4*)(tot + (size_t)m * 256 + lane * 4);
    bf16x4 v1 = *(const bf16x4*)(tot + (size_t)(4096 + m) * 256 + lane * 4);
    float f00 = v0[0], f01 = v0[1], f02 = v0[2], f03 = v0[3];
    float f10 = v1[0], f11 = v1[1], f12 = v1[2], f13 = v1[3];
    float s0 = f00 * f00 + f01 * f01 + f02 * f02 + f03 * f03;
    float s1 = f10 * f10 + f11 * f11 + f12 * f12 + f13 * f13;
    for (int off = 32; off; off >>= 1) {
      s0 += __shfl_down(s0, off, 64);
      s1 += __shfl_down(s1, off, 64);
    }
    if (lane == 0) { sq[m] = s0; sq[4096 + m] = s1; bsq += s0 + s1; }
    c0 += f00 + f10; c1 += f01 + f11; c2 += f02 + f12; c3 += f03 + f13;
    float2 gv = *(const float2*)(gates + m * 2);
    float4 r;
    r.x = gv.x * f00 + gv.y * f10;
    r.y = gv.x * f01 + gv.y * f11;
    r.z = gv.x * f02 + gv.y * f12;
    r.w = gv.x * f03 + gv.y * f13;
    *(float4*)(out + (size_t)m * 256 + lane * 4) = r;
  }
  lcol[wave][lane * 4 + 0] = c0;
  lcol[wave][lane * 4 + 1] = c1;
  lcol[wave][lane * 4 + 2] = c2;
  lcol[wave][lane * 4 + 3] = c3;
  if (lane == 0) wsq[wave] = bsq;
  __syncthreads();
  float s2 = lcol[0][t] + lcol[1][t] + lcol[2][t] + lcol[3][t];
  atomicAdd(&colsum[t], s2);
  if (t == 0) atomicAdd(&scal[4], wsq[0] + wsq[1] + wsq[2] + wsq[3]);
  __threadfence();
  if (t == 0) {
    unsigned int c = atomicAdd((unsigned int*)(scal + 5), 1u);
    isLast = (c == 127u) ? 1u : 0u;
  }
  __syncthreads();
  if (isLast) {
    __threadfence();
    float cv = atomicAdd(&colsum[t], 0.0f);      // coherent read
    lcol[0][t] = cv * cv;
    __syncthreads();
    for (int off = 128; off; off >>= 1) {
      if (t < off) lcol[0][t] += lcol[0][t + off];
      __syncthreads();
    }
    if (t == 0) {
      float sumsq = atomicAdd(&scal[4], 0.0f);
      double sumdist = 2.0 * 8192.0 * (double)sumsq - 2.0 * (double)lcol[0][0];
      double bw = sumdist / (8192.0 * 8192.0 - 8192.0) / 4.0;  // / KERNEL_MUL^(5//2)
      scal[1] = (float)(1.4426950408889634 / (bw * 16.0));     // g4 * log2(e)
      scal[2] = (float)bw;
    }
  }
}

// ---------------- Gram tiles + fused multi-bandwidth kernel sum ---------------
// R2-EXACT structure (measured 48.3 us, best of 5 structures tried):
// double-buffered LDS, prefetch DMAs issued before compute, plain
// __syncthreads (its vmcnt(0) drain lands the prefetch under the MFMA phase).
// No setprio, no raw barriers, no counted vmcnt (all three regressed: R3-R5).
// Pre-swizzled DMA source + XOR read swizzle: 0 bank conflicts (verified).
// Last block (atomic counter) writes the final scalar.
__global__ __launch_bounds__(256) void k_gram(const __bf16* __restrict__ tot,
                                              const float* __restrict__ sq,
                                              const float* __restrict__ scal,
                                              float* __restrict__ Ssum,
                                              float* __restrict__ out) {
  const int b = blockIdx.x;                    // 0..2079
  const int nid = (b & 7) * 260 + (b >> 3);    // XCD-chunked, bijective (2080=8*260)
  int ti = (int)((129.0 - sqrt(129.0 * 129.0 - 8.0 * (double)nid)) * 0.5);
  while (64 * ti - ti * (ti - 1) / 2 > nid) --ti;
  while (64 * (ti + 1) - (ti + 1) * ti / 2 <= nid) ++ti;
  const int tj = ti + (nid - (64 * ti - ti * (ti - 1) / 2));

  __shared__ __bf16 As[2][128][64];
  __shared__ __bf16 Bs[2][128][64];
  __shared__ float sqi[128], sqj[128];
  __shared__ float wred[4];
  const int t = threadIdx.x;
  const int wid = t >> 6, lane = t & 63;
  const int wr = wid >> 1, wc = wid & 1;
  const int n16 = lane & 15, q = lane >> 4;
  const int sx = (n16 & 7) << 3;     // read-side swizzle (element units)
  const int lr = lane >> 3;          // 0..7: row within 8-row DMA chunk
  const int ls = lane & 7;           // 0..7: 16B slot within row

  const float g = scal[1];           // log2e / (bw*16)
  if (t < 128) sqi[t] = sq[ti * 128 + t] * g;          // pre-scaled by g
  else         sqj[t - 128] = sq[tj * 128 + (t - 128)] * g;

  f32x4 acc[4][4];
  f32x4 zero = {0.f, 0.f, 0.f, 0.f};
  for (int i = 0; i < 4; ++i)
    for (int j = 0; j < 4; ++j) acc[i][j] = zero;

  // pre-swizzled per-lane global source: LDS slot ls of row r holds global
  // slot ls^(r&7); r&7 == lr for every chunk (rows step by 8).
  const __bf16* gA = tot + (size_t)(ti * 128 + wid * 32 + lr) * 256 + ((ls ^ lr) << 3);
  const __bf16* gB = tot + (size_t)(tj * 128 + wid * 32 + lr) * 256 + ((ls ^ lr) << 3);

  // prologue: stage chunk 0 into buffer 0 (wave wid covers rows wid*32..+32)
#pragma unroll
  for (int p = 0; p < 4; ++p) {
    gload_lds16(gA + p * 8 * 256, &As[0][wid * 32 + p * 8][0]);
    gload_lds16(gB + p * 8 * 256, &Bs[0][wid * 32 + p * 8][0]);
  }
  __syncthreads();   // implicit vmcnt(0): buffer 0 ready

  int buf = 0;
  for (int it = 0; it < 4; ++it) {
    // issue async DMA for next K-chunk into the other buffer
    if (it < 3) {
      const int kc = (it + 1) * 64;
#pragma unroll
      for (int p = 0; p < 4; ++p) {
        gload_lds16(gA + p * 8 * 256 + kc, &As[buf ^ 1][wid * 32 + p * 8][0]);
        gload_lds16(gB + p * 8 * 256 + kc, &Bs[buf ^ 1][wid * 32 + p * 8][0]);
      }
    }
    // compute current buffer (loads fly under the MFMAs)
#pragma unroll
    for (int ks = 0; ks < 2; ++ks) {
      bf16x8 af[4], bfr[4];
#pragma unroll
      for (int f = 0; f < 4; ++f) {
        af[f]  = *(const bf16x8*)&As[buf][wr * 64 + f * 16 + n16][(ks * 32 + q * 8) ^ sx];
        bfr[f] = *(const bf16x8*)&Bs[buf][wc * 64 + f * 16 + n16][(ks * 32 + q * 8) ^ sx];
      }
      for (int fr = 0; fr < 4; ++fr)
        for (int fc = 0; fc < 4; ++fc)
          acc[fr][fc] = __builtin_amdgcn_mfma_f32_16x16x32_bf16(af[fr], bfr[fc], acc[fr][fc], 0, 0, 0);
    }
    __syncthreads();   // drains prefetch DMA (vmcnt 0) + protects buffer reuse
    buf ^= 1;
  }

  // epilogue: arg = 2g*acc - (g*si + g*sj); ksum = u+u2+u4+u8+u16, u=exp2(arg)
  const float twog = 2.f * g;
  float lsum = 0.f;
  for (int fr = 0; fr < 4; ++fr) {
    for (int r = 0; r < 4; ++r) {
      float gsi = sqi[wr * 64 + fr * 16 + q * 4 + r];
      for (int fc = 0; fc < 4; ++fc) {
        float gsj = sqj[wc * 64 + fc * 16 + n16];
        float u = exp2f(fmaf(twog, acc[fr][fc][r], -(gsi + gsj)));
        float u2 = u * u, u4 = u2 * u2, u8 = u4 * u4;
        float s1 = fmaf(u8, u8, u8);           // u16 + u8
        lsum += (u + u2) + (u4 + s1);
      }
    }
  }
  for (int off = 32; off; off >>= 1) lsum += __shfl_down(lsum, off, 64);
  if (lane == 0) wred[wid] = lsum;
  __syncthreads();
  if (t == 0) {
    float blocksum = wred[0] + wred[1] + wred[2] + wred[3];
    float sgn = ((ti < 32) == (tj < 32)) ? 1.f : -1.f;
    float wgt = (ti == tj) ? sgn : 2.f * sgn;
    atomicAdd(Ssum, wgt * blocksum);
    __threadfence();
    unsigned int* cnt = (unsigned int*)(Ssum + 3);   // scal[3], zeroed by k_gates
    unsigned int c = atomicAdd(cnt, 1u);
    if (c == 2079u) {
      float totS = atomicAdd(Ssum, 0.0f);            // coherent read of full sum
      out[1048576] = -(totS / 16777216.0f);
    }
  }
}

extern "C" void kernel_launch(void* const* d_in, const int* in_sizes, int n_in,
                              void* d_out, int out_size, void* d_ws, size_t ws_size,
                              hipStream_t stream) {
  const float* x    = (const float*)d_in[0];
  const float* Waux = (const float*)d_in[1];
  const float* baux = (const float*)d_in[2];
  const float* W    = (const float*)d_in[3];
  const float* bias = (const float*)d_in[4];
  float* out = (float*)d_out;

  char* ws = (char*)d_ws;
  __bf16* totalbf = (__bf16*)ws;                    // 8192*256*2 = 4,194,304 B
  float* sq      = (float*)(ws + 4194304);          // 8192 f32
  float* colsum  = (float*)(ws + 4227072);          // 256 f32
  float* scal    = (float*)(ws + 4228096);          // [0]=Ssum [1]=g4l2 [2]=bw [3]=gram-cnt [4]=sumsq [5]=sqc-cnt
  float* gates   = (float*)(ws + 4228160);          // 4096*2 f32

  k_gates<<<1024, 256, 0, stream>>>(x, Waux, baux, gates, colsum, scal);
  k_outs<<<dim3(8, 64), 256, 0, stream>>>(x, W, bias, totalbf);
  k_sqc<<<128, 256, 0, stream>>>(totalbf, gates, sq, colsum, scal, out);
  k_gram<<<2080, 256, 0, stream>>>(totalbf, sq, scal, scal, out);
}

// Round 7
// 143.773 us; speedup vs baseline: 1.3687x; 1.2081x over previous
//
#include <hip/hip_runtime.h>
#include <stdint.h>
#include <math.h>

typedef __attribute__((ext_vector_type(8))) __bf16 bf16x8;
typedef __attribute__((ext_vector_type(4))) __bf16 bf16x4;
typedef __attribute__((ext_vector_type(4))) float f32x4;

// async global->LDS 16B DMA (no VGPR round-trip). LDS dest must be
// wave-uniform base; HW writes lane i at base + i*16.
__device__ __forceinline__ void gload_lds16(const __bf16* g, __bf16* l) {
  __builtin_amdgcn_global_load_lds(
      (const __attribute__((address_space(1))) unsigned int*)g,
      (__attribute__((address_space(3))) unsigned int*)l,
      16, 0, 0);
}

// ---------------- gates: softmax(x @ W_aux^T + b_aux) ----------------
// block 0 also zeroes the atomic accumulators (replaces the memset node).
__global__ __launch_bounds__(256) void k_gates(const float* __restrict__ x,
                                               const float* __restrict__ Waux,
                                               const float* __restrict__ baux,
                                               float* __restrict__ gates,
                                               float* __restrict__ colsum,
                                               float* __restrict__ scal) {
  if (blockIdx.x == 0) {
    colsum[threadIdx.x] = 0.f;
    if (threadIdx.x < 8) scal[threadIdx.x] = 0.f;
  }
  const int wave = threadIdx.x >> 6;
  const int lane = threadIdx.x & 63;
  const int row = blockIdx.x * 4 + wave;
  const float4* xr = (const float4*)(x + (size_t)row * 512);
  const float4* w0 = (const float4*)(Waux);
  const float4* w1 = (const float4*)(Waux + 512);
  float p0 = 0.f, p1 = 0.f;
  for (int c = lane; c < 128; c += 64) {
    float4 xv = xr[c];
    float4 a = w0[c], b = w1[c];
    p0 += xv.x * a.x + xv.y * a.y + xv.z * a.z + xv.w * a.w;
    p1 += xv.x * b.x + xv.y * b.y + xv.z * b.z + xv.w * b.w;
  }
  for (int off = 32; off; off >>= 1) {
    p0 += __shfl_down(p0, off, 64);
    p1 += __shfl_down(p1, off, 64);
  }
  if (lane == 0) {
    p0 += baux[0]; p1 += baux[1];
    float m = fmaxf(p0, p1);
    float e0 = __expf(p0 - m), e1 = __expf(p1 - m);
    float inv = 1.f / (e0 + e1);
    gates[row * 2 + 0] = e0 * inv;
    gates[row * 2 + 1] = e1 * inv;
  }
}

// ---------------- outs GEMM: C[m][n] = sum_k x[m][k] * Wflat[n][k] + bias[n] ----
// M=4096, N=512, K=512. 64x64 tiles -> grid (8,64)=512 blocks.
__global__ __launch_bounds__(256) void k_outs(const float* __restrict__ x,
                                              const float* __restrict__ W,
                                              const float* __restrict__ bias,
                                              __bf16* __restrict__ totalbf) {
  __shared__ __bf16 As[64][64];
  __shared__ __bf16 Bs[64][64];
  const int bj = blockIdx.x;   // 0..7  (N tiles of 64)
  const int bi = blockIdx.y;   // 0..63 (M tiles of 64)
  const int t = threadIdx.x;
  const int wid = t >> 6, lane = t & 63;
  const int wr = wid >> 1, wc = wid & 1;
  const int n16 = lane & 15, q = lane >> 4;
  const int sx = (n16 & 7) << 3;        // read-side swizzle (element units)
  const int erow = t >> 4;              // 0..15 (+p*16)
  const int c4 = (t & 15) << 2;         // 0..60

  f32x4 acc[2][2];
  f32x4 zero = {0.f, 0.f, 0.f, 0.f};
  for (int i = 0; i < 2; ++i)
    for (int j = 0; j < 2; ++j) acc[i][j] = zero;

  const int arow0 = bi * 64, brow0 = bj * 64;

  float4 ra[4], rb[4];
#pragma unroll
  for (int p = 0; p < 4; ++p) {
    int row = p * 16 + erow;
    ra[p] = *(const float4*)(x + (size_t)(arow0 + row) * 512 + c4);
    rb[p] = *(const float4*)(W + (size_t)(brow0 + row) * 512 + c4);
  }

  for (int kc = 0; kc < 512; kc += 64) {
#pragma unroll
    for (int p = 0; p < 4; ++p) {
      int row = p * 16 + erow;
      int col = c4 ^ ((row & 7) << 3);
      float4 va = ra[p];
      bf16x4 ba = {(__bf16)va.x, (__bf16)va.y, (__bf16)va.z, (__bf16)va.w};
      *(bf16x4*)&As[row][col] = ba;
      float4 vb = rb[p];
      bf16x4 bb = {(__bf16)vb.x, (__bf16)vb.y, (__bf16)vb.z, (__bf16)vb.w};
      *(bf16x4*)&Bs[row][col] = bb;
    }
    __syncthreads();
    // issue next-tile global loads AFTER the barrier: they fly under the MFMAs
    if (kc < 448) {
#pragma unroll
      for (int p = 0; p < 4; ++p) {
        int row = p * 16 + erow;
        ra[p] = *(const float4*)(x + (size_t)(arow0 + row) * 512 + kc + 64 + c4);
        rb[p] = *(const float4*)(W + (size_t)(brow0 + row) * 512 + kc + 64 + c4);
      }
    }
#pragma unroll
    for (int ks = 0; ks < 2; ++ks) {
      bf16x8 af[2], bfr[2];
#pragma unroll
      for (int f = 0; f < 2; ++f) {
        af[f]  = *(const bf16x8*)&As[wr * 32 + f * 16 + n16][(ks * 32 + q * 8) ^ sx];
        bfr[f] = *(const bf16x8*)&Bs[wc * 32 + f * 16 + n16][(ks * 32 + q * 8) ^ sx];
      }
      for (int fr = 0; fr < 2; ++fr)
        for (int fc = 0; fc < 2; ++fc)
          acc[fr][fc] = __builtin_amdgcn_mfma_f32_16x16x32_bf16(af[fr], bfr[fc], acc[fr][fc], 0, 0, 0);
    }
    __syncthreads();
  }

  for (int fc = 0; fc < 2; ++fc) {
    int n_g = bj * 64 + wc * 32 + fc * 16 + n16;   // 0..511
    float bv = bias[n_g];
    int l = n_g >> 8, o = n_g & 255;
    for (int fr = 0; fr < 2; ++fr) {
      for (int r = 0; r < 4; ++r) {
        int m_g = bi * 64 + wr * 32 + fr * 16 + q * 4 + r;
        float v = acc[fr][fc][r] + bv;
        totalbf[(size_t)(l * 4096 + m_g) * 256 + o] = (__bf16)v;
      }
    }
  }
}

// ------- fused: sq + colsum + combine + bandwidth finalize (last block) -------
__global__ __launch_bounds__(256) void k_sqc(const __bf16* __restrict__ tot,
                                             const float* __restrict__ gates,
                                             float* __restrict__ sq,
                                             float* __restrict__ colsum,
                                             float* __restrict__ scal,
                                             float* __restrict__ out) {
  __shared__ float lcol[4][256];
  __shared__ float wsq[4];
  __shared__ unsigned int isLast;
  const int t = threadIdx.x;
  const int wave = t >> 6, lane = t & 63;
  float c0 = 0.f, c1 = 0.f, c2 = 0.f, c3 = 0.f;
  float bsq = 0.f;
  for (int it = 0; it < 8; ++it) {
    int m = blockIdx.x * 32 + wave * 8 + it;      // 0..4095
    bf16x4 v0 = *(const bf16x4*)(tot + (size_t)m * 256 + lane * 4);
    bf16x4 v1 = *(const bf16x4*)(tot + (size_t)(4096 + m) * 256 + lane * 4);
    float f00 = v0[0], f01 = v0[1], f02 = v0[2], f03 = v0[3];
    float f10 = v1[0], f11 = v1[1], f12 = v1[2], f13 = v1[3];
    float s0 = f00 * f00 + f01 * f01 + f02 * f02 + f03 * f03;
    float s1 = f10 * f10 + f11 * f11 + f12 * f12 + f13 * f13;
    for (int off = 32; off; off >>= 1) {
      s0 += __shfl_down(s0, off, 64);
      s1 += __shfl_down(s1, off, 64);
    }
    if (lane == 0) { sq[m] = s0; sq[4096 + m] = s1; bsq += s0 + s1; }
    c0 += f00 + f10; c1 += f01 + f11; c2 += f02 + f12; c3 += f03 + f13;
    float2 gv = *(const float2*)(gates + m * 2);
    float4 r;
    r.x = gv.x * f00 + gv.y * f10;
    r.y = gv.x * f01 + gv.y * f11;
    r.z = gv.x * f02 + gv.y * f12;
    r.w = gv.x * f03 + gv.y * f13;
    *(float4*)(out + (size_t)m * 256 + lane * 4) = r;
  }
  lcol[wave][lane * 4 + 0] = c0;
  lcol[wave][lane * 4 + 1] = c1;
  lcol[wave][lane * 4 + 2] = c2;
  lcol[wave][lane * 4 + 3] = c3;
  if (lane == 0) wsq[wave] = bsq;
  __syncthreads();
  float s2 = lcol[0][t] + lcol[1][t] + lcol[2][t] + lcol[3][t];
  atomicAdd(&colsum[t], s2);
  if (t == 0) atomicAdd(&scal[4], wsq[0] + wsq[1] + wsq[2] + wsq[3]);
  __threadfence();
  if (t == 0) {
    unsigned int c = atomicAdd((unsigned int*)(scal + 5), 1u);
    isLast = (c == 127u) ? 1u : 0u;
  }
  __syncthreads();
  if (isLast) {
    __threadfence();
    float cv = atomicAdd(&colsum[t], 0.0f);      // coherent read
    lcol[0][t] = cv * cv;
    __syncthreads();
    for (int off = 128; off; off >>= 1) {
      if (t < off) lcol[0][t] += lcol[0][t + off];
      __syncthreads();
    }
    if (t == 0) {
      float sumsq = atomicAdd(&scal[4], 0.0f);
      double sumdist = 2.0 * 8192.0 * (double)sumsq - 2.0 * (double)lcol[0][0];
      double bw = sumdist / (8192.0 * 8192.0 - 8192.0) / 4.0;  // / KERNEL_MUL^(5//2)
      scal[1] = (float)(1.4426950408889634 / (bw * 16.0));     // g4 * log2(e)
      scal[2] = (float)bw;
    }
  }
}

// ---------------- Gram tiles + fused multi-bandwidth kernel sum ---------------
// R2 structure: double-buffered LDS, prefetch DMAs issued before compute,
// plain __syncthreads. NO finalizer tail — R3-R6 showed the blocking
// same-address atomic counter + __threadfence tail costs ~30 us across 2080
// blocks (serialized cross-XCD RMWs at block retire); single fire-and-forget
// atomicAdd only, final scalar moved back to a 1-thread kernel.
__global__ __launch_bounds__(256) void k_gram(const __bf16* __restrict__ tot,
                                              const float* __restrict__ sq,
                                              const float* __restrict__ scal,
                                              float* __restrict__ Ssum) {
  const int b = blockIdx.x;                    // 0..2079
  const int nid = (b & 7) * 260 + (b >> 3);    // XCD-chunked, bijective (2080=8*260)
  int ti = (int)((129.0 - sqrt(129.0 * 129.0 - 8.0 * (double)nid)) * 0.5);
  while (64 * ti - ti * (ti - 1) / 2 > nid) --ti;
  while (64 * (ti + 1) - (ti + 1) * ti / 2 <= nid) ++ti;
  const int tj = ti + (nid - (64 * ti - ti * (ti - 1) / 2));

  __shared__ __bf16 As[2][128][64];
  __shared__ __bf16 Bs[2][128][64];
  __shared__ float sqi[128], sqj[128];
  __shared__ float wred[4];
  const int t = threadIdx.x;
  const int wid = t >> 6, lane = t & 63;
  const int wr = wid >> 1, wc = wid & 1;
  const int n16 = lane & 15, q = lane >> 4;
  const int sx = (n16 & 7) << 3;     // read-side swizzle (element units)
  const int lr = lane >> 3;          // 0..7: row within 8-row DMA chunk
  const int ls = lane & 7;           // 0..7: 16B slot within row

  const float g = scal[1];           // log2e / (bw*16)
  if (t < 128) sqi[t] = sq[ti * 128 + t] * g;          // pre-scaled by g
  else         sqj[t - 128] = sq[tj * 128 + (t - 128)] * g;

  f32x4 acc[4][4];
  f32x4 zero = {0.f, 0.f, 0.f, 0.f};
  for (int i = 0; i < 4; ++i)
    for (int j = 0; j < 4; ++j) acc[i][j] = zero;

  // pre-swizzled per-lane global source: LDS slot ls of row r holds global
  // slot ls^(r&7); r&7 == lr for every chunk (rows step by 8).
  const __bf16* gA = tot + (size_t)(ti * 128 + wid * 32 + lr) * 256 + ((ls ^ lr) << 3);
  const __bf16* gB = tot + (size_t)(tj * 128 + wid * 32 + lr) * 256 + ((ls ^ lr) << 3);

  // prologue: stage chunk 0 into buffer 0 (wave wid covers rows wid*32..+32)
#pragma unroll
  for (int p = 0; p < 4; ++p) {
    gload_lds16(gA + p * 8 * 256, &As[0][wid * 32 + p * 8][0]);
    gload_lds16(gB + p * 8 * 256, &Bs[0][wid * 32 + p * 8][0]);
  }
  __syncthreads();   // implicit vmcnt(0): buffer 0 ready

  int buf = 0;
  for (int it = 0; it < 4; ++it) {
    // issue async DMA for next K-chunk into the other buffer
    if (it < 3) {
      const int kc = (it + 1) * 64;
#pragma unroll
      for (int p = 0; p < 4; ++p) {
        gload_lds16(gA + p * 8 * 256 + kc, &As[buf ^ 1][wid * 32 + p * 8][0]);
        gload_lds16(gB + p * 8 * 256 + kc, &Bs[buf ^ 1][wid * 32 + p * 8][0]);
      }
    }
    // compute current buffer (loads fly under the MFMAs)
#pragma unroll
    for (int ks = 0; ks < 2; ++ks) {
      bf16x8 af[4], bfr[4];
#pragma unroll
      for (int f = 0; f < 4; ++f) {
        af[f]  = *(const bf16x8*)&As[buf][wr * 64 + f * 16 + n16][(ks * 32 + q * 8) ^ sx];
        bfr[f] = *(const bf16x8*)&Bs[buf][wc * 64 + f * 16 + n16][(ks * 32 + q * 8) ^ sx];
      }
      for (int fr = 0; fr < 4; ++fr)
        for (int fc = 0; fc < 4; ++fc)
          acc[fr][fc] = __builtin_amdgcn_mfma_f32_16x16x32_bf16(af[fr], bfr[fc], acc[fr][fc], 0, 0, 0);
    }
    __syncthreads();   // drains prefetch DMA (vmcnt 0) + protects buffer reuse
    buf ^= 1;
  }

  // epilogue: arg = 2g*acc - (g*si + g*sj); ksum = u+u2+u4+u8+u16, u=exp2(arg)
  const float twog = 2.f * g;
  float lsum = 0.f;
  for (int fr = 0; fr < 4; ++fr) {
    for (int r = 0; r < 4; ++r) {
      float gsi = sqi[wr * 64 + fr * 16 + q * 4 + r];
      for (int fc = 0; fc < 4; ++fc) {
        float gsj = sqj[wc * 64 + fc * 16 + n16];
        float u = exp2f(fmaf(twog, acc[fr][fc][r], -(gsi + gsj)));
        float u2 = u * u, u4 = u2 * u2, u8 = u4 * u4;
        float s1 = fmaf(u8, u8, u8);           // u16 + u8
        lsum += (u + u2) + (u4 + s1);
      }
    }
  }
  for (int off = 32; off; off >>= 1) lsum += __shfl_down(lsum, off, 64);
  if (lane == 0) wred[wid] = lsum;
  __syncthreads();
  if (t == 0) {
    float blocksum = wred[0] + wred[1] + wred[2] + wred[3];
    float sgn = ((ti < 32) == (tj < 32)) ? 1.f : -1.f;
    float wgt = (ti == tj) ? sgn : 2.f * sgn;
    atomicAdd(Ssum, wgt * blocksum);   // fire-and-forget, no fence, no counter
  }
}

// ---------------- final scalar: -mean = -S / B^2 ------------------------------
__global__ void k_final(const float* __restrict__ scal, float* __restrict__ out) {
  out[1048576] = -(scal[0] / 16777216.0f);
}

extern "C" void kernel_launch(void* const* d_in, const int* in_sizes, int n_in,
                              void* d_out, int out_size, void* d_ws, size_t ws_size,
                              hipStream_t stream) {
  const float* x    = (const float*)d_in[0];
  const float* Waux = (const float*)d_in[1];
  const float* baux = (const float*)d_in[2];
  const float* W    = (const float*)d_in[3];
  const float* bias = (const float*)d_in[4];
  float* out = (float*)d_out;

  char* ws = (char*)d_ws;
  __bf16* totalbf = (__bf16*)ws;                    // 8192*256*2 = 4,194,304 B
  float* sq      = (float*)(ws + 4194304);          // 8192 f32
  float* colsum  = (float*)(ws + 4227072);          // 256 f32
  float* scal    = (float*)(ws + 4228096);          // [0]=Ssum [1]=g4l2 [2]=bw [3]=unused [4]=sumsq [5]=sqc-cnt
  float* gates   = (float*)(ws + 4228160);          // 4096*2 f32

  k_gates<<<1024, 256, 0, stream>>>(x, Waux, baux, gates, colsum, scal);
  k_outs<<<dim3(8, 64), 256, 0, stream>>>(x, W, bias, totalbf);
  k_sqc<<<128, 256, 0, stream>>>(totalbf, gates, sq, colsum, scal, out);
  k_gram<<<2080, 256, 0, stream>>>(totalbf, sq, scal, scal);
  k_final<<<1, 1, 0, stream>>>(scal, out);
}

// Round 8
// 141.766 us; speedup vs baseline: 1.3881x; 1.0142x over previous
//
#include <hip/hip_runtime.h>
#include <stdint.h>
#include <math.h>

typedef __attribute__((ext_vector_type(8))) __bf16 bf16x8;
typedef __attribute__((ext_vector_type(4))) __bf16 bf16x4;
typedef __attribute__((ext_vector_type(4))) float f32x4;

// async global->LDS 16B DMA (no VGPR round-trip). LDS dest must be
// wave-uniform base; HW writes lane i at base + i*16.
__device__ __forceinline__ void gload_lds16(const __bf16* g, __bf16* l) {
  __builtin_amdgcn_global_load_lds(
      (const __attribute__((address_space(1))) unsigned int*)g,
      (__attribute__((address_space(3))) unsigned int*)l,
      16, 0, 0);
}

// ---------------- outs GEMM: C[m][n] = sum_k x[m][k] * Wflat[n][k] + bias[n] ----
// M=4096, N=512, K=512. 64x64 tiles -> grid (8,64)=512 blocks.
// Block (0,0) also zero-inits the atomic accumulators + final scalar
// (runs first in stream order; replaces the old k_gates zeroing).
__global__ __launch_bounds__(256) void k_outs(const float* __restrict__ x,
                                              const float* __restrict__ W,
                                              const float* __restrict__ bias,
                                              __bf16* __restrict__ totalbf,
                                              float* __restrict__ colsum,
                                              float* __restrict__ scal,
                                              float* __restrict__ out) {
  __shared__ __bf16 As[64][64];
  __shared__ __bf16 Bs[64][64];
  const int bj = blockIdx.x;   // 0..7  (N tiles of 64)
  const int bi = blockIdx.y;   // 0..63 (M tiles of 64)
  const int t = threadIdx.x;
  if (bj == 0 && bi == 0) {
    colsum[t] = 0.f;
    if (t < 8) scal[t] = 0.f;
    if (t == 0) out[1048576] = 0.f;
  }
  const int wid = t >> 6, lane = t & 63;
  const int wr = wid >> 1, wc = wid & 1;
  const int n16 = lane & 15, q = lane >> 4;
  const int sx = (n16 & 7) << 3;        // read-side swizzle (element units)
  const int erow = t >> 4;              // 0..15 (+p*16)
  const int c4 = (t & 15) << 2;         // 0..60

  f32x4 acc[2][2];
  f32x4 zero = {0.f, 0.f, 0.f, 0.f};
  for (int i = 0; i < 2; ++i)
    for (int j = 0; j < 2; ++j) acc[i][j] = zero;

  const int arow0 = bi * 64, brow0 = bj * 64;

  float4 ra[4], rb[4];
#pragma unroll
  for (int p = 0; p < 4; ++p) {
    int row = p * 16 + erow;
    ra[p] = *(const float4*)(x + (size_t)(arow0 + row) * 512 + c4);
    rb[p] = *(const float4*)(W + (size_t)(brow0 + row) * 512 + c4);
  }

  for (int kc = 0; kc < 512; kc += 64) {
#pragma unroll
    for (int p = 0; p < 4; ++p) {
      int row = p * 16 + erow;
      int col = c4 ^ ((row & 7) << 3);
      float4 va = ra[p];
      bf16x4 ba = {(__bf16)va.x, (__bf16)va.y, (__bf16)va.z, (__bf16)va.w};
      *(bf16x4*)&As[row][col] = ba;
      float4 vb = rb[p];
      bf16x4 bb = {(__bf16)vb.x, (__bf16)vb.y, (__bf16)vb.z, (__bf16)vb.w};
      *(bf16x4*)&Bs[row][col] = bb;
    }
    __syncthreads();
    // issue next-tile global loads AFTER the barrier: they fly under the MFMAs
    if (kc < 448) {
#pragma unroll
      for (int p = 0; p < 4; ++p) {
        int row = p * 16 + erow;
        ra[p] = *(const float4*)(x + (size_t)(arow0 + row) * 512 + kc + 64 + c4);
        rb[p] = *(const float4*)(W + (size_t)(brow0 + row) * 512 + kc + 64 + c4);
      }
    }
#pragma unroll
    for (int ks = 0; ks < 2; ++ks) {
      bf16x8 af[2], bfr[2];
#pragma unroll
      for (int f = 0; f < 2; ++f) {
        af[f]  = *(const bf16x8*)&As[wr * 32 + f * 16 + n16][(ks * 32 + q * 8) ^ sx];
        bfr[f] = *(const bf16x8*)&Bs[wc * 32 + f * 16 + n16][(ks * 32 + q * 8) ^ sx];
      }
      for (int fr = 0; fr < 2; ++fr)
        for (int fc = 0; fc < 2; ++fc)
          acc[fr][fc] = __builtin_amdgcn_mfma_f32_16x16x32_bf16(af[fr], bfr[fc], acc[fr][fc], 0, 0, 0);
    }
    __syncthreads();
  }

  for (int fc = 0; fc < 2; ++fc) {
    int n_g = bj * 64 + wc * 32 + fc * 16 + n16;   // 0..511
    float bv = bias[n_g];
    int l = n_g >> 8, o = n_g & 255;
    for (int fr = 0; fr < 2; ++fr) {
      for (int r = 0; r < 4; ++r) {
        int m_g = bi * 64 + wr * 32 + fr * 16 + q * 4 + r;
        float v = acc[fr][fc][r] + bv;
        totalbf[(size_t)(l * 4096 + m_g) * 256 + o] = (__bf16)v;
      }
    }
  }
}

// ------- fused: gates + sq + colsum + combine + bandwidth finalize ------------
// 128 blocks x 256 thr; wave w owns rows blk*32+w*8..+8 — it computes the
// GATES for exactly those rows in-register (butterfly shfl_xor reduce puts the
// dot-products in ALL lanes; no LDS, no sync), then uses them in the combine.
// k_gates kernel + gates global round-trip eliminated.
__global__ __launch_bounds__(256) void k_sqc(const __bf16* __restrict__ tot,
                                             const float* __restrict__ x,
                                             const float* __restrict__ Waux,
                                             const float* __restrict__ baux,
                                             float* __restrict__ sq,
                                             float* __restrict__ colsum,
                                             float* __restrict__ scal,
                                             float* __restrict__ out) {
  __shared__ float lcol[4][256];
  __shared__ float wsq[4];
  __shared__ unsigned int isLast;
  const int t = threadIdx.x;
  const int wave = t >> 6, lane = t & 63;

  // ---- gates phase: rows m = blk*32 + wave*8 + it ----
  const float4* wa = (const float4*)(Waux);          // row 0: 128 float4
  const float4* wb = (const float4*)(Waux + 512);    // row 1
  float4 a0 = wa[lane * 2], a1 = wa[lane * 2 + 1];
  float4 b0 = wb[lane * 2], b1 = wb[lane * 2 + 1];
  const float bx0 = baux[0], bx1 = baux[1];
  float g0[8], g1[8];
#pragma unroll
  for (int it = 0; it < 8; ++it) {
    int m = blockIdx.x * 32 + wave * 8 + it;
    const float4* xr = (const float4*)(x + (size_t)m * 512);
    float4 x0 = xr[lane * 2], x1 = xr[lane * 2 + 1];
    float p0 = x0.x * a0.x + x0.y * a0.y + x0.z * a0.z + x0.w * a0.w
             + x1.x * a1.x + x1.y * a1.y + x1.z * a1.z + x1.w * a1.w;
    float p1 = x0.x * b0.x + x0.y * b0.y + x0.z * b0.z + x0.w * b0.w
             + x1.x * b1.x + x1.y * b1.y + x1.z * b1.z + x1.w * b1.w;
    for (int off = 32; off; off >>= 1) {
      p0 += __shfl_xor(p0, off, 64);
      p1 += __shfl_xor(p1, off, 64);
    }
    p0 += bx0; p1 += bx1;
    float mm = fmaxf(p0, p1);
    float e0 = __expf(p0 - mm), e1 = __expf(p1 - mm);
    float inv = 1.f / (e0 + e1);
    g0[it] = e0 * inv;
    g1[it] = e1 * inv;
  }

  // ---- sq + colsum + combine ----
  float c0 = 0.f, c1 = 0.f, c2 = 0.f, c3 = 0.f;
  float bsq = 0.f;
#pragma unroll
  for (int it = 0; it < 8; ++it) {
    int m = blockIdx.x * 32 + wave * 8 + it;      // 0..4095
    bf16x4 v0 = *(const bf16x4*)(tot + (size_t)m * 256 + lane * 4);
    bf16x4 v1 = *(const bf16x4*)(tot + (size_t)(4096 + m) * 256 + lane * 4);
    float f00 = v0[0], f01 = v0[1], f02 = v0[2], f03 = v0[3];
    float f10 = v1[0], f11 = v1[1], f12 = v1[2], f13 = v1[3];
    float s0 = f00 * f00 + f01 * f01 + f02 * f02 + f03 * f03;
    float s1 = f10 * f10 + f11 * f11 + f12 * f12 + f13 * f13;
    for (int off = 32; off; off >>= 1) {
      s0 += __shfl_down(s0, off, 64);
      s1 += __shfl_down(s1, off, 64);
    }
    if (lane == 0) { sq[m] = s0; sq[4096 + m] = s1; bsq += s0 + s1; }
    c0 += f00 + f10; c1 += f01 + f11; c2 += f02 + f12; c3 += f03 + f13;
    float4 r;
    r.x = g0[it] * f00 + g1[it] * f10;
    r.y = g0[it] * f01 + g1[it] * f11;
    r.z = g0[it] * f02 + g1[it] * f12;
    r.w = g0[it] * f03 + g1[it] * f13;
    *(float4*)(out + (size_t)m * 256 + lane * 4) = r;
  }
  lcol[wave][lane * 4 + 0] = c0;
  lcol[wave][lane * 4 + 1] = c1;
  lcol[wave][lane * 4 + 2] = c2;
  lcol[wave][lane * 4 + 3] = c3;
  if (lane == 0) wsq[wave] = bsq;
  __syncthreads();
  float s2 = lcol[0][t] + lcol[1][t] + lcol[2][t] + lcol[3][t];
  atomicAdd(&colsum[t], s2);
  if (t == 0) atomicAdd(&scal[4], wsq[0] + wsq[1] + wsq[2] + wsq[3]);
  __threadfence();
  if (t == 0) {
    unsigned int c = atomicAdd((unsigned int*)(scal + 5), 1u);
    isLast = (c == 127u) ? 1u : 0u;
  }
  __syncthreads();
  if (isLast) {
    __threadfence();
    float cv = atomicAdd(&colsum[t], 0.0f);      // coherent read
    lcol[0][t] = cv * cv;
    __syncthreads();
    for (int off = 128; off; off >>= 1) {
      if (t < off) lcol[0][t] += lcol[0][t + off];
      __syncthreads();
    }
    if (t == 0) {
      float sumsq = atomicAdd(&scal[4], 0.0f);
      double sumdist = 2.0 * 8192.0 * (double)sumsq - 2.0 * (double)lcol[0][0];
      double bw = sumdist / (8192.0 * 8192.0 - 8192.0) / 4.0;  // / KERNEL_MUL^(5//2)
      scal[1] = (float)(1.4426950408889634 / (bw * 16.0));     // g4 * log2(e)
      scal[2] = (float)bw;
    }
  }
}

// ---------------- Gram tiles + fused multi-bandwidth kernel sum ---------------
// R7-proven structure (47.9 us): double-buffered LDS, prefetch DMAs issued
// before compute, plain __syncthreads, fire-and-forget atomic only.
// The final -S/2^24 scale is folded into each block's atomicAdd weight so the
// sum lands directly in out[1048576] — no counter tail (cost ~30 us in R3-R6),
// no k_final kernel.
__global__ __launch_bounds__(256) void k_gram(const __bf16* __restrict__ tot,
                                              const float* __restrict__ sq,
                                              const float* __restrict__ scal,
                                              float* __restrict__ out) {
  const int b = blockIdx.x;                    // 0..2079
  const int nid = (b & 7) * 260 + (b >> 3);    // XCD-chunked, bijective (2080=8*260)
  int ti = (int)((129.0 - sqrt(129.0 * 129.0 - 8.0 * (double)nid)) * 0.5);
  while (64 * ti - ti * (ti - 1) / 2 > nid) --ti;
  while (64 * (ti + 1) - (ti + 1) * ti / 2 <= nid) ++ti;
  const int tj = ti + (nid - (64 * ti - ti * (ti - 1) / 2));

  __shared__ __bf16 As[2][128][64];
  __shared__ __bf16 Bs[2][128][64];
  __shared__ float sqi[128], sqj[128];
  __shared__ float wred[4];
  const int t = threadIdx.x;
  const int wid = t >> 6, lane = t & 63;
  const int wr = wid >> 1, wc = wid & 1;
  const int n16 = lane & 15, q = lane >> 4;
  const int sx = (n16 & 7) << 3;     // read-side swizzle (element units)
  const int lr = lane >> 3;          // 0..7: row within 8-row DMA chunk
  const int ls = lane & 7;           // 0..7: 16B slot within row

  const float g = scal[1];           // log2e / (bw*16)
  if (t < 128) sqi[t] = sq[ti * 128 + t] * g;          // pre-scaled by g
  else         sqj[t - 128] = sq[tj * 128 + (t - 128)] * g;

  f32x4 acc[4][4];
  f32x4 zero = {0.f, 0.f, 0.f, 0.f};
  for (int i = 0; i < 4; ++i)
    for (int j = 0; j < 4; ++j) acc[i][j] = zero;

  // pre-swizzled per-lane global source: LDS slot ls of row r holds global
  // slot ls^(r&7); r&7 == lr for every chunk (rows step by 8).
  const __bf16* gA = tot + (size_t)(ti * 128 + wid * 32 + lr) * 256 + ((ls ^ lr) << 3);
  const __bf16* gB = tot + (size_t)(tj * 128 + wid * 32 + lr) * 256 + ((ls ^ lr) << 3);

  // prologue: stage chunk 0 into buffer 0 (wave wid covers rows wid*32..+32)
#pragma unroll
  for (int p = 0; p < 4; ++p) {
    gload_lds16(gA + p * 8 * 256, &As[0][wid * 32 + p * 8][0]);
    gload_lds16(gB + p * 8 * 256, &Bs[0][wid * 32 + p * 8][0]);
  }
  __syncthreads();   // implicit vmcnt(0): buffer 0 ready

  int buf = 0;
  for (int it = 0; it < 4; ++it) {
    // issue async DMA for next K-chunk into the other buffer
    if (it < 3) {
      const int kc = (it + 1) * 64;
#pragma unroll
      for (int p = 0; p < 4; ++p) {
        gload_lds16(gA + p * 8 * 256 + kc, &As[buf ^ 1][wid * 32 + p * 8][0]);
        gload_lds16(gB + p * 8 * 256 + kc, &Bs[buf ^ 1][wid * 32 + p * 8][0]);
      }
    }
    // compute current buffer (loads fly under the MFMAs)
#pragma unroll
    for (int ks = 0; ks < 2; ++ks) {
      bf16x8 af[4], bfr[4];
#pragma unroll
      for (int f = 0; f < 4; ++f) {
        af[f]  = *(const bf16x8*)&As[buf][wr * 64 + f * 16 + n16][(ks * 32 + q * 8) ^ sx];
        bfr[f] = *(const bf16x8*)&Bs[buf][wc * 64 + f * 16 + n16][(ks * 32 + q * 8) ^ sx];
      }
      for (int fr = 0; fr < 4; ++fr)
        for (int fc = 0; fc < 4; ++fc)
          acc[fr][fc] = __builtin_amdgcn_mfma_f32_16x16x32_bf16(af[fr], bfr[fc], acc[fr][fc], 0, 0, 0);
    }
    __syncthreads();   // drains prefetch DMA (vmcnt 0) + protects buffer reuse
    buf ^= 1;
  }

  // epilogue: arg = 2g*acc - (g*si + g*sj); ksum = u+u2+u4+u8+u16, u=exp2(arg)
  const float twog = 2.f * g;
  float lsum = 0.f;
  for (int fr = 0; fr < 4; ++fr) {
    for (int r = 0; r < 4; ++r) {
      float gsi = sqi[wr * 64 + fr * 16 + q * 4 + r];
      for (int fc = 0; fc < 4; ++fc) {
        float gsj = sqj[wc * 64 + fc * 16 + n16];
        float u = exp2f(fmaf(twog, acc[fr][fc][r], -(gsi + gsj)));
        float u2 = u * u, u4 = u2 * u2, u8 = u4 * u4;
        float s1 = fmaf(u8, u8, u8);           // u16 + u8
        lsum += (u + u2) + (u4 + s1);
      }
    }
  }
  for (int off = 32; off; off >>= 1) lsum += __shfl_down(lsum, off, 64);
  if (lane == 0) wred[wid] = lsum;
  __syncthreads();
  if (t == 0) {
    float blocksum = wred[0] + wred[1] + wred[2] + wred[3];
    float sgn = ((ti < 32) == (tj < 32)) ? 1.f : -1.f;
    float wgt = (ti == tj) ? sgn : 2.f * sgn;
    // final scale folded in: out[1048576] = -S/2^24, accumulated directly
    atomicAdd(out + 1048576, wgt * blocksum * (-1.f / 16777216.f));
  }
}

extern "C" void kernel_launch(void* const* d_in, const int* in_sizes, int n_in,
                              void* d_out, int out_size, void* d_ws, size_t ws_size,
                              hipStream_t stream) {
  const float* x    = (const float*)d_in[0];
  const float* Waux = (const float*)d_in[1];
  const float* baux = (const float*)d_in[2];
  const float* W    = (const float*)d_in[3];
  const float* bias = (const float*)d_in[4];
  float* out = (float*)d_out;

  char* ws = (char*)d_ws;
  __bf16* totalbf = (__bf16*)ws;                    // 8192*256*2 = 4,194,304 B
  float* sq      = (float*)(ws + 4194304);          // 8192 f32
  float* colsum  = (float*)(ws + 4227072);          // 256 f32
  float* scal    = (float*)(ws + 4228096);          // [1]=g4l2 [2]=bw [4]=sumsq [5]=sqc-cnt

  k_outs<<<dim3(8, 64), 256, 0, stream>>>(x, W, bias, totalbf, colsum, scal, out);
  k_sqc<<<128, 256, 0, stream>>>(totalbf, x, Waux, baux, sq, colsum, scal, out);
  k_gram<<<2080, 256, 0, stream>>>(totalbf, sq, scal, out);
}